// Round 22
// baseline (208.376 us; speedup 1.0000x reference)
//
#include <hip/hip_runtime.h>
#include <hip/hip_fp16.h>

// ---------------------------------------------------------------------------
// 2-layer GCN (PyG GCNConv): deg^{-1/2} sym norm with self-loops.
// Round 22 = L2-RESIDENT slices + 16-deep gather MLP (combining r11/r17's
// layout regime with r21's pipelining regime).
//   r21 evidence: paired (64B) layout is L2-miss-BW-bound (FETCH 206MB,
//   3.6TB/s, deeper MLP gained 3%). r11/r17 evidence: 16-col slices are
//   L2-resident (FETCH 59MB) but 8-deep latency-bound (74.7us). This round:
//   - xhT[8][N+1][16] fp16 (3.2MB/slice -> one XCD L2, blockIdx&7 -> XCD);
//     gather waves = 8 nodes x 8 lanes; 16-edge batches: 2 index regs
//     prefetched a batch ahead, 16 independent 32B loads issued before any
//     accumulation, 2 fdot2 chains. pdeg x16 -> no masks/ballots.
//   - thT[4][N+1][16] for layer 2 (2 XCDs/slice, still L2-resident).
//   - CSR build = r21: binA fixed-stride buckets + per-bucket scatB
//     (x16 padding, shfl scan); dummy index N -> zeroed payload row.
//   - mgemm_fused (r17 form): aggT-(W1,b1,relu)->LDS-(W2,*dinv)->thT.
// ---------------------------------------------------------------------------

#define NT 256
#define KE 8            // edges per thread in binA
#define CAP 20480       // pairs capacity per bucket (actual ~12.5k)
#define SCAP 35872      // srcs slots per bucket (>= CAP + 15*1024 + 16)

typedef _Float16 half8 __attribute__((ext_vector_type(8)));
typedef _Float16 h2 __attribute__((ext_vector_type(2)));
typedef float floatx4 __attribute__((ext_vector_type(4)));

#if __has_builtin(__builtin_amdgcn_fdot2)
__device__ __forceinline__ float dot2f(h2 a, h2 b, float c) {
    return __builtin_amdgcn_fdot2(a, b, c, false);
}
#else
__device__ __forceinline__ float dot2f(h2 a, h2 b, float c) {
    return c + (float)a.x * (float)b.x + (float)a.y * (float)b.y;
}
#endif

// ---- phase A: bin edges into fixed-stride bucket regions ----
__global__ __launch_bounds__(NT) void binA_k(
    const int* __restrict__ src, const int* __restrict__ dst,
    int* __restrict__ bktcur, unsigned* __restrict__ pairs, int e) {
    __shared__ int lh[128];
    __shared__ int lbase[128];
    int tid = threadIdx.x;
    if (tid < 128) lh[tid] = 0;
    __syncthreads();
    int base = blockIdx.x * (NT * KE);
    int sv[KE];
    unsigned meta[KE];
#pragma unroll
    for (int k = 0; k < KE; ++k) {
        int ei = base + k * NT + tid;
        if (ei < e) {
            int d = dst[ei];
            sv[k] = src[ei];
            int b = d >> 10;
            int lr = atomicAdd(&lh[b], 1);  // LDS atomic
            meta[k] = ((unsigned)b << 22) | ((unsigned)lr << 10) | (unsigned)(d & 1023);
        } else {
            sv[k] = 0;
            meta[k] = 0xffffffffu;
        }
    }
    __syncthreads();
    if (tid < 128 && lh[tid] > 0)
        lbase[tid] = atomicAdd(&bktcur[tid], lh[tid]);  // <=128 global/block
    __syncthreads();
#pragma unroll
    for (int k = 0; k < KE; ++k) {
        if (meta[k] != 0xffffffffu) {
            int b = (int)(meta[k] >> 22);
            int lr = (int)((meta[k] >> 10) & 0xfffu);
            pairs[(size_t)b * CAP + lbase[b] + lr] =
                ((unsigned)sv[k] << 10) | (meta[k] & 1023u);
        }
    }
}

// ---- phase B: per-bucket CSR build + scatter (1 block = 1 bucket) ----
__global__ __launch_bounds__(1024) void scatB_k(
    const unsigned* __restrict__ pairs, const int* __restrict__ bktcur,
    int* __restrict__ rowptr, int* __restrict__ pdeg, float* __restrict__ dinv,
    int* __restrict__ srcs, int n) {
    __shared__ int lc[1024];
    __shared__ int wpart[16], wpref[16];
    const int i = blockIdx.x;                 // 0..127
    const int b = (i & 7) * 16 + (i >> 3);    // bucket, XCD-local regions
    const int tid = threadIdx.x;
    const int nbase = b << 10;
    if (nbase >= n) return;
    const int cntb = bktcur[b];
    const size_t pbase = (size_t)b * CAP;
    const size_t sbase = (size_t)b * SCAP;

    lc[tid] = 0;
    __syncthreads();
    for (int j = tid; j < cntb; j += 1024)
        atomicAdd(&lc[pairs[pbase + j] & 1023u], 1);
    __syncthreads();

    const int c  = lc[tid];
    const int pv = (c + 15) & ~15;  // x16 padding for 16-edge gather batches

    // inclusive scan of pv: shfl within wave, serial over 16 wave partials
    int x = pv;
#pragma unroll
    for (int off = 1; off < 64; off <<= 1) {
        int t = __shfl_up(x, off, 64);
        if ((tid & 63) >= off) x += t;
    }
    if ((tid & 63) == 63) wpart[tid >> 6] = x;
    __syncthreads();
    if (tid < 16) {
        int s = 0;
        for (int j = 0; j <= tid; ++j) s += wpart[j];
        wpref[tid] = s;
    }
    __syncthreads();
    const int oex = x - pv + ((tid >= 64) ? wpref[(tid >> 6) - 1] : 0);
    const int total = wpref[15];

    const int d = nbase + tid;
    if (d < n) {
        rowptr[d] = (int)sbase + oex;
        pdeg[d]   = pv;
        dinv[d]   = rsqrtf((float)(c + 1));  // +1 self-loop
    }
    lc[tid] = oex;  // per-dst placement cursor
    __syncthreads();

    for (int j = tid; j < cntb; j += 1024) {
        unsigned p = pairs[pbase + j];
        int dl = (int)(p & 1023u);
        int pos = atomicAdd(&lc[dl], 1);
        srcs[sbase + pos] = (int)(p >> 10);
    }
    __syncthreads();

    // pads: [oex+c, oex+pv) per dst; +16 tail slack after bucket total
    for (int k = oex + c; k < oex + pv; ++k) srcs[sbase + k] = n;
    if (tid < 16) srcs[sbase + total + tid] = n;
}

// ---------------- conv1T: x -> xhT[8][N+1][16] fp16 (row N zeroed) ---------
__global__ void conv1T_k(const float* __restrict__ x, const float* __restrict__ dinv,
                         __half* __restrict__ xhT, int n) {
    int t = blockIdx.x * NT + threadIdx.x;
    int node = t >> 3;
    if (node > n) return;
    int q = t & 7;
    int4 o0, o1;
    if (node == n) {
        o0 = make_int4(0, 0, 0, 0);
        o1 = o0;
    } else {
        float dn = dinv[node];
        const float4* xp =
            reinterpret_cast<const float4*>(x + (size_t)node * 128 + q * 16);
        __half2 h[8];
#pragma unroll
        for (int j = 0; j < 4; ++j) {
            float4 a = xp[j];
            h[2 * j + 0] = __floats2half2_rn(a.x * dn, a.y * dn);
            h[2 * j + 1] = __floats2half2_rn(a.z * dn, a.w * dn);
        }
        o0 = reinterpret_cast<int4*>(h)[0];
        o1 = reinterpret_cast<int4*>(h)[1];
    }
    int4* op = reinterpret_cast<int4*>(xhT + ((size_t)q * (n + 1) + node) * 16);
    op[0] = o0;
    op[1] = o1;
}

// ---------------- sliced gathers, 8 nodes x 8 lanes, 16-edge batches -------
// Payload: [slice][N+1][16] fp16 -> 32 B per node per slice; row N zeros.
// Per 16-edge batch: 2 index loads (prefetched a batch ahead), 16 shfl
// broadcasts, 16 INDEPENDENT 32B-row loads issued before any accumulation,
// then 32 fdot2 over 2 chains. pdeg is x16 so no masks/ballots.

__global__ __launch_bounds__(NT) void gatherT128_k(
    const int* __restrict__ rowptr, const int* __restrict__ pdeg,
    const int* __restrict__ srcs, const float* __restrict__ dinv,
    const __half* __restrict__ xhT, __half2* __restrict__ aggT, int n) {
    const int slice = blockIdx.x & 7;
    const int chunk = blockIdx.x >> 3;
    const int lane  = threadIdx.x & 63;
    const int wid   = threadIdx.x >> 6;
    const int g     = lane >> 3;   // node sub-group 0..7
    const int c     = lane & 7;    // half2 col within slice / srcs sub-index
    const int node  = chunk * 32 + wid * 8 + g;
    if (node >= n) return;  // shfl sources stay within each 8-lane group

    const int e0 = rowptr[node];
    const int pd = pdeg[node];
    const char* base = (const char*)(xhT + (size_t)slice * (n + 1) * 16);
    const unsigned c4 = (unsigned)c * 4u;
    const h2 b10 = {(_Float16)1.0f, (_Float16)0.0f};
    const h2 b01 = {(_Float16)0.0f, (_Float16)1.0f};

    // self-loop
    h2 fs = *(const h2*)(base + (size_t)node * 32 + c4);
    float ax0 = dot2f(fs, b10, 0.0f), ay0 = dot2f(fs, b01, 0.0f);
    float ax1 = 0.0f, ay1 = 0.0f;

    int sA = srcs[e0 + c];
    int sB = srcs[e0 + 8 + c];
    for (int jb = 0; jb < pd; jb += 16) {
        int nA = srcs[e0 + jb + 16 + c];  // in-bounds: padded + 16 slack
        int nB = srcs[e0 + jb + 24 + c];
        h2 f[16];
#pragma unroll
        for (int u = 0; u < 8; ++u) {
            int s = __shfl(sA, (g << 3) | u, 64);
            f[u] = *(const h2*)(base + (unsigned)s * 32u + c4);
        }
#pragma unroll
        for (int u = 0; u < 8; ++u) {
            int s = __shfl(sB, (g << 3) | u, 64);
            f[8 + u] = *(const h2*)(base + (unsigned)s * 32u + c4);
        }
#pragma unroll
        for (int u = 0; u < 8; ++u) {
            ax0 = dot2f(f[u], b10, ax0);
            ay0 = dot2f(f[u], b01, ay0);
            ax1 = dot2f(f[8 + u], b10, ax1);
            ay1 = dot2f(f[8 + u], b01, ay1);
        }
        sA = nA;
        sB = nB;
    }

    float dn = dinv[node];
    aggT[((size_t)slice * n + node) * 8 + c] =
        __floats2half2_rn((ax0 + ax1) * dn, (ay0 + ay1) * dn);
}

// gatherT64: thT[4][N+1][16]; q8 -> (slice = q8>>1, node-half = q8&1).
// Writes row-major fp32 out directly (+b2): slice = one 64B line per row.
__global__ __launch_bounds__(NT) void gatherT64_k(
    const int* __restrict__ rowptr, const int* __restrict__ pdeg,
    const int* __restrict__ srcs, const float* __restrict__ dinv,
    const __half* __restrict__ thT, const float* __restrict__ b2,
    float* __restrict__ out, int n) {
    const int q8    = blockIdx.x & 7;
    const int slice = q8 >> 1;
    const int chunk = blockIdx.x >> 3;
    const int lane  = threadIdx.x & 63;
    const int wid   = threadIdx.x >> 6;
    const int g     = lane >> 3;
    const int c     = lane & 7;
    const int node  = chunk * 64 + (q8 & 1) * 32 + wid * 8 + g;
    if (node >= n) return;

    const int e0 = rowptr[node];
    const int pd = pdeg[node];
    const char* base = (const char*)(thT + (size_t)slice * (n + 1) * 16);
    const unsigned c4 = (unsigned)c * 4u;
    const h2 b10 = {(_Float16)1.0f, (_Float16)0.0f};
    const h2 b01 = {(_Float16)0.0f, (_Float16)1.0f};

    h2 fs = *(const h2*)(base + (size_t)node * 32 + c4);
    float ax0 = dot2f(fs, b10, 0.0f), ay0 = dot2f(fs, b01, 0.0f);
    float ax1 = 0.0f, ay1 = 0.0f;

    int sA = srcs[e0 + c];
    int sB = srcs[e0 + 8 + c];
    for (int jb = 0; jb < pd; jb += 16) {
        int nA = srcs[e0 + jb + 16 + c];
        int nB = srcs[e0 + jb + 24 + c];
        h2 f[16];
#pragma unroll
        for (int u = 0; u < 8; ++u) {
            int s = __shfl(sA, (g << 3) | u, 64);
            f[u] = *(const h2*)(base + (unsigned)s * 32u + c4);
        }
#pragma unroll
        for (int u = 0; u < 8; ++u) {
            int s = __shfl(sB, (g << 3) | u, 64);
            f[8 + u] = *(const h2*)(base + (unsigned)s * 32u + c4);
        }
#pragma unroll
        for (int u = 0; u < 8; ++u) {
            ax0 = dot2f(f[u], b10, ax0);
            ay0 = dot2f(f[u], b01, ay0);
            ax1 = dot2f(f[8 + u], b10, ax1);
            ay1 = dot2f(f[8 + u], b01, ay1);
        }
        sA = nA;
        sB = nB;
    }

    float dn = dinv[node];
    int col = slice * 16 + c * 2;
    *reinterpret_cast<float2*>(&out[(size_t)node * 64 + col]) =
        make_float2((ax0 + ax1) * dn + b2[col], (ay0 + ay1) * dn + b2[col + 1]);
}

// ---------------- fused MLP: thT = (relu(aggT@W1 + b1) @ W2) * dinv --------
__global__ __launch_bounds__(NT) void mgemm_fused_k(
    const __half* __restrict__ aggT, const float* __restrict__ W1,
    const float* __restrict__ b1, const float* __restrict__ W2,
    const float* __restrict__ dinv, __half* __restrict__ thT, int n) {
    __shared__ _Float16 h1s[64][136];

    const int wid  = threadIdx.x >> 6;
    const int lane = threadIdx.x & 63;
    const int lrow = lane & 15;
    const int kgrp = lane >> 4;

    if (blockIdx.x == 0 && threadIdx.x < 64) {
        int sl = threadIdx.x >> 4, j = threadIdx.x & 15;
        thT[((size_t)sl * (n + 1) + n) * 16 + j] = __float2half(0.0f);
    }

    half8 bf1[2][4];
    float bv[2];
#pragma unroll
    for (int nt = 0; nt < 2; ++nt) {
        int col = wid * 32 + nt * 16 + lrow;
#pragma unroll
        for (int kk = 0; kk < 4; ++kk)
#pragma unroll
            for (int j = 0; j < 8; ++j)
                bf1[nt][kk][j] = (_Float16)W1[(size_t)(kk * 32 + kgrp * 8 + j) * 128 + col];
        bv[nt] = b1[col];
    }
    half8 bf2[4];
    {
        int col = wid * 16 + lrow;
#pragma unroll
        for (int kk = 0; kk < 4; ++kk)
#pragma unroll
            for (int j = 0; j < 8; ++j)
                bf2[kk][j] = (_Float16)W2[(size_t)(kk * 32 + kgrp * 8 + j) * 64 + col];
    }

    const int m0 = blockIdx.x * 64;

    floatx4 acc1[4][2];
#pragma unroll
    for (int mt = 0; mt < 4; ++mt)
#pragma unroll
        for (int nt = 0; nt < 2; ++nt) acc1[mt][nt] = floatx4{0.f, 0.f, 0.f, 0.f};

#pragma unroll
    for (int kk = 0; kk < 4; ++kk) {
        const int k0 = kk * 32 + kgrp * 8;
        half8 af[4];
#pragma unroll
        for (int mt = 0; mt < 4; ++mt) {
            int row = m0 + mt * 16 + lrow;
            if (row >= n) row = n - 1;  // clamp; final stores guarded
            af[mt] = *reinterpret_cast<const half8*>(
                &aggT[(((size_t)(k0 >> 4)) * n + row) * 16 + (k0 & 15)]);
        }
#pragma unroll
        for (int mt = 0; mt < 4; ++mt)
#pragma unroll
            for (int nt = 0; nt < 2; ++nt)
                acc1[mt][nt] = __builtin_amdgcn_mfma_f32_16x16x32_f16(
                    af[mt], bf1[nt][kk], acc1[mt][nt], 0, 0, 0);
    }

#pragma unroll
    for (int mt = 0; mt < 4; ++mt) {
#pragma unroll
        for (int r = 0; r < 4; ++r) {
            int rloc = mt * 16 + kgrp * 4 + r;
#pragma unroll
            for (int nt = 0; nt < 2; ++nt) {
                float v = fmaxf(acc1[mt][nt][r] + bv[nt], 0.0f);
                h1s[rloc][wid * 32 + nt * 16 + lrow] = (_Float16)v;
            }
        }
    }
    __syncthreads();

    floatx4 acc2[4];
#pragma unroll
    for (int mt = 0; mt < 4; ++mt) acc2[mt] = floatx4{0.f, 0.f, 0.f, 0.f};

#pragma unroll
    for (int kk = 0; kk < 4; ++kk) {
        const int k0 = kk * 32 + kgrp * 8;
#pragma unroll
        for (int mt = 0; mt < 4; ++mt) {
            half8 af = *reinterpret_cast<const half8*>(&h1s[mt * 16 + lrow][k0]);
            acc2[mt] = __builtin_amdgcn_mfma_f32_16x16x32_f16(
                af, bf2[kk], acc2[mt], 0, 0, 0);
        }
    }

#pragma unroll
    for (int mt = 0; mt < 4; ++mt) {
#pragma unroll
        for (int r = 0; r < 4; ++r) {
            int row = m0 + mt * 16 + kgrp * 4 + r;
            if (row < n) {
                float v = acc2[mt][r] * dinv[row];
                thT[((size_t)wid * (n + 1) + row) * 16 + lrow] = __float2half(v);
            }
        }
    }
}

// ---------------------------------------------------------------------------

extern "C" void kernel_launch(void* const* d_in, const int* in_sizes, int n_in,
                              void* d_out, int out_size, void* d_ws, size_t ws_size,
                              hipStream_t stream) {
    const float* x   = (const float*)d_in[0];
    const int*   ei  = (const int*)d_in[1];
    const float* W1  = (const float*)d_in[2];
    const float* b1  = (const float*)d_in[3];
    const float* W2  = (const float*)d_in[4];
    const float* b2  = (const float*)d_in[5];
    float*       out = (float*)d_out;

    const int N = in_sizes[0] / 128;
    const int E = in_sizes[1] / 2;
    const int* srcp = ei;      // edge_index[0]
    const int* dstp = ei + E;  // edge_index[1]

    // workspace (512B-aligned):
    //   dinv[N] | pdeg[N] | rowptr[N] | bktcur[128] | srcs[128*SCAP]
    //   | xhT[8][N+1][16] fp16 | aggT[8][N][16] fp16
    //   | thT[4][N+1][16] fp16  (pairs[128*CAP] u32 aliases thT: 10.5<12.8MB)
    char* ws = (char*)d_ws;
    size_t off = 0;
    auto alloc = [&](size_t bytes) {
        char* p = ws + off;
        off = (off + bytes + 511) & ~(size_t)511;
        return p;
    };
    float*  dinv   = (float*)alloc((size_t)N * 4);
    int*    pdeg   = (int*)alloc((size_t)N * 4);
    int*    rowptr = (int*)alloc((size_t)N * 4);
    int*    bktcur = (int*)alloc(128 * 4);
    int*    srcs   = (int*)alloc((size_t)128 * SCAP * 4);
    __half* xhT    = (__half*)alloc((size_t)(N + 1) * 128 * 2);
    __half* aggT   = (__half*)alloc((size_t)N * 128 * 2);
    __half* thT    = (__half*)alloc((size_t)(N + 1) * 64 * 2);
    unsigned* pairs = (unsigned*)thT;  // alias: dead until mgemm_fused

    // ---- CSR build: bin -> per-bucket build+scatter ----
    hipMemsetAsync(bktcur, 0, 128 * 4, stream);
    binA_k<<<(E + NT * KE - 1) / (NT * KE), NT, 0, stream>>>(
        srcp, dstp, bktcur, pairs, E);
    scatB_k<<<128, 1024, 0, stream>>>(pairs, bktcur, rowptr, pdeg, dinv, srcs, N);

    // ---- layer 1: xhT (dummy row zeroed) -> aggT ----
    conv1T_k<<<((N + 1) * 8 + NT - 1) / NT, NT, 0, stream>>>(x, dinv, xhT, N);
    gatherT128_k<<<((N + 31) / 32) * 8, NT, 0, stream>>>(
        rowptr, pdeg, srcs, dinv, xhT, (__half2*)aggT, N);

    // ---- fused MLP: aggT -> thT = (relu(aggT@W1+b1)@W2)*dinv ----
    mgemm_fused_k<<<(N + 63) / 64, NT, 0, stream>>>(
        aggT, W1, b1, W2, dinv, thT, N);

    // ---- layer 2 gather -> out (+b2) ----
    gatherT64_k<<<((N + 63) / 64) * 8, NT, 0, stream>>>(
        rowptr, pdeg, srcs, dinv, thT, b2, out, N);
}

// Round 23
// 197.919 us; speedup vs baseline: 1.0528x; 1.0528x over previous
//
#include <hip/hip_runtime.h>
#include <hip/hip_fp16.h>

// ---------------------------------------------------------------------------
// 2-layer GCN (PyG GCNConv): deg^{-1/2} sym norm with self-loops.
// Round 23 = revert to round 21 (measured best, 198.3us).
//   r22 falsified "L2-resident slices + deep MLP": sliced layout is
//   request-count-bound (74.5us at both 8- and 16-deep); paired layout is
//   L2-miss-BW-bound (65.5us, 3.6TB/s). Paired + 16-deep is the optimum of
//   all 8 measured gather structures.
//   - 2-kernel CSR build: binA (fixed-stride buckets, LDS histogram) +
//     scatB (per-bucket count/scan/place/pad, x16 padding, shfl scan).
//   - xhP[4][N+1][32] fp16 pair-slices; 16-lane groups read 64B/edge.
//   - 16-edge batches: 2 index regs prefetched a batch ahead, 16 independent
//     loads issued before accumulation, 2 fdot2 chains. Dummy index N ->
//     zeroed payload row: no masks/ballots.
//   - mgemm_fused: aggT -(W1,b1,relu)-> LDS -(W2,*dinv)-> thP.
//   - gatherT64 on thP[2][N+1][32], writes row-major out (+b2).
// ---------------------------------------------------------------------------

#define NT 256
#define KE 8            // edges per thread in binA
#define CAP 20480       // pairs capacity per bucket (actual ~12.5k)
#define SCAP 35872      // srcs slots per bucket (>= CAP + 15*1024 + 16)

typedef _Float16 half8 __attribute__((ext_vector_type(8)));
typedef _Float16 h2 __attribute__((ext_vector_type(2)));
typedef float floatx4 __attribute__((ext_vector_type(4)));

#if __has_builtin(__builtin_amdgcn_fdot2)
__device__ __forceinline__ float dot2f(h2 a, h2 b, float c) {
    return __builtin_amdgcn_fdot2(a, b, c, false);
}
#else
__device__ __forceinline__ float dot2f(h2 a, h2 b, float c) {
    return c + (float)a.x * (float)b.x + (float)a.y * (float)b.y;
}
#endif

// ---- phase A: bin edges into fixed-stride bucket regions ----
// pair word = (src << 10) | (dst & 1023); bucket = dst >> 10.
// bktcur[128] holds count cursors (pre-zeroed via memsetAsync).
__global__ __launch_bounds__(NT) void binA_k(
    const int* __restrict__ src, const int* __restrict__ dst,
    int* __restrict__ bktcur, unsigned* __restrict__ pairs, int e) {
    __shared__ int lh[128];
    __shared__ int lbase[128];
    int tid = threadIdx.x;
    if (tid < 128) lh[tid] = 0;
    __syncthreads();
    int base = blockIdx.x * (NT * KE);
    int sv[KE];
    unsigned meta[KE];
#pragma unroll
    for (int k = 0; k < KE; ++k) {
        int ei = base + k * NT + tid;
        if (ei < e) {
            int d = dst[ei];
            sv[k] = src[ei];
            int b = d >> 10;
            int lr = atomicAdd(&lh[b], 1);  // LDS atomic
            meta[k] = ((unsigned)b << 22) | ((unsigned)lr << 10) | (unsigned)(d & 1023);
        } else {
            sv[k] = 0;
            meta[k] = 0xffffffffu;
        }
    }
    __syncthreads();
    if (tid < 128 && lh[tid] > 0)
        lbase[tid] = atomicAdd(&bktcur[tid], lh[tid]);  // <=128 global/block
    __syncthreads();
#pragma unroll
    for (int k = 0; k < KE; ++k) {
        if (meta[k] != 0xffffffffu) {
            int b = (int)(meta[k] >> 22);
            int lr = (int)((meta[k] >> 10) & 0xfffu);
            pairs[(size_t)b * CAP + lbase[b] + lr] =
                ((unsigned)sv[k] << 10) | (meta[k] & 1023u);
        }
    }
}

// ---- phase B: per-bucket CSR build + scatter (1 block = 1 bucket) ----
// 1024 threads. Emits dinv, pdeg (x16-padded), rowptr (absolute,
// bucket-strided srcs), places srcs, fills pads (+16 tail slack).
__global__ __launch_bounds__(1024) void scatB_k(
    const unsigned* __restrict__ pairs, const int* __restrict__ bktcur,
    int* __restrict__ rowptr, int* __restrict__ pdeg, float* __restrict__ dinv,
    int* __restrict__ srcs, int n) {
    __shared__ int lc[1024];
    __shared__ int wpart[16], wpref[16];
    const int i = blockIdx.x;                 // 0..127
    const int b = (i & 7) * 16 + (i >> 3);    // bucket, XCD-local regions
    const int tid = threadIdx.x;
    const int nbase = b << 10;
    if (nbase >= n) return;
    const int cntb = bktcur[b];
    const size_t pbase = (size_t)b * CAP;
    const size_t sbase = (size_t)b * SCAP;

    lc[tid] = 0;
    __syncthreads();
    for (int j = tid; j < cntb; j += 1024)
        atomicAdd(&lc[pairs[pbase + j] & 1023u], 1);
    __syncthreads();

    const int c  = lc[tid];
    const int pv = (c + 15) & ~15;  // x16 padding for 16-edge gather batches

    // inclusive scan of pv: shfl within wave, serial over 16 wave partials
    int x = pv;
#pragma unroll
    for (int off = 1; off < 64; off <<= 1) {
        int t = __shfl_up(x, off, 64);
        if ((tid & 63) >= off) x += t;
    }
    if ((tid & 63) == 63) wpart[tid >> 6] = x;
    __syncthreads();
    if (tid < 16) {
        int s = 0;
        for (int j = 0; j <= tid; ++j) s += wpart[j];
        wpref[tid] = s;
    }
    __syncthreads();
    const int oex = x - pv + ((tid >= 64) ? wpref[(tid >> 6) - 1] : 0);
    const int total = wpref[15];

    const int d = nbase + tid;
    if (d < n) {
        rowptr[d] = (int)sbase + oex;
        pdeg[d]   = pv;
        dinv[d]   = rsqrtf((float)(c + 1));  // +1 self-loop
    }
    lc[tid] = oex;  // per-dst placement cursor
    __syncthreads();

    for (int j = tid; j < cntb; j += 1024) {
        unsigned p = pairs[pbase + j];
        int dl = (int)(p & 1023u);
        int pos = atomicAdd(&lc[dl], 1);
        srcs[sbase + pos] = (int)(p >> 10);
    }
    __syncthreads();

    // pads: [oex+c, oex+pv) per dst; +16 tail slack after bucket total
    for (int k = oex + c; k < oex + pv; ++k) srcs[sbase + k] = n;
    if (tid < 16) srcs[sbase + total + tid] = n;
}

// ---------------- conv1T: x -> xhP[4][N+1][32] fp16 (row N zeroed) ---------
__global__ void conv1T_k(const float* __restrict__ x, const float* __restrict__ dinv,
                         __half* __restrict__ xhP, int n) {
    int t = blockIdx.x * NT + threadIdx.x;
    int node = t >> 3;
    if (node > n) return;
    int q = t & 7;
    int4 o0, o1;
    if (node == n) {
        o0 = make_int4(0, 0, 0, 0);
        o1 = o0;
    } else {
        float dn = dinv[node];
        const float4* xp =
            reinterpret_cast<const float4*>(x + (size_t)node * 128 + q * 16);
        __half2 h[8];
#pragma unroll
        for (int j = 0; j < 4; ++j) {
            float4 a = xp[j];
            h[2 * j + 0] = __floats2half2_rn(a.x * dn, a.y * dn);
            h[2 * j + 1] = __floats2half2_rn(a.z * dn, a.w * dn);
        }
        o0 = reinterpret_cast<int4*>(h)[0];
        o1 = reinterpret_cast<int4*>(h)[1];
    }
    int4* op = reinterpret_cast<int4*>(
        xhP + ((size_t)(q >> 1) * (n + 1) + node) * 32 + (q & 1) * 16);
    op[0] = o0;
    op[1] = o1;
}

// ---------------- paired gathers: 16-lane groups, 16-edge batches ----------
// xhP/thP: [pair][N+1][32] fp16 -> 64 B per node per pair; row N zeros.
// Per 16-edge batch: 2 index loads (prefetched a batch ahead), 16 shfl
// broadcasts, 16 INDEPENDENT 64B loads issued before any accumulation,
// then 32 fdot2 over 2 chains. pdeg is x16 so no masks/ballots.

__global__ __launch_bounds__(NT) void gatherT128_k(
    const int* __restrict__ rowptr, const int* __restrict__ pdeg,
    const int* __restrict__ srcs, const float* __restrict__ dinv,
    const __half* __restrict__ xhP, __half2* __restrict__ aggT, int n) {
    const int q8    = blockIdx.x & 7;   // (pair, node-16-block parity)
    const int pair  = q8 & 3;
    const int chunk = blockIdx.x >> 3;
    const int lane  = threadIdx.x & 63;
    const int wid   = threadIdx.x >> 6;
    const int g     = lane >> 4;   // node sub-group 0..3
    const int c     = lane & 15;   // half2 col within 32-col pair
    const int node  = chunk * 32 + (q8 >> 2) * 16 + wid * 4 + g;
    if (node >= n) return;  // uniform within each 16-lane group

    const int e0 = rowptr[node];
    const int pd = pdeg[node];
    const char* base = (const char*)(xhP + (size_t)pair * (n + 1) * 32);
    const unsigned c4 = (unsigned)c * 4u;
    const int c7 = c & 7;
    const h2 b10 = {(_Float16)1.0f, (_Float16)0.0f};
    const h2 b01 = {(_Float16)0.0f, (_Float16)1.0f};

    // self-loop (64 B row)
    h2 fs = *(const h2*)(base + (size_t)node * 64 + c4);
    float ax0 = dot2f(fs, b10, 0.0f), ay0 = dot2f(fs, b01, 0.0f);
    float ax1 = 0.0f, ay1 = 0.0f;

    int sA = srcs[e0 + c7];
    int sB = srcs[e0 + 8 + c7];
    for (int jb = 0; jb < pd; jb += 16) {
        int nA = srcs[e0 + jb + 16 + c7];  // in-bounds: padded + 16 slack
        int nB = srcs[e0 + jb + 24 + c7];
        h2 f[16];
#pragma unroll
        for (int u = 0; u < 8; ++u) {
            int s = __shfl(sA, (lane & 0x30) | u, 64);
            f[u] = *(const h2*)(base + (unsigned)s * 64u + c4);
        }
#pragma unroll
        for (int u = 0; u < 8; ++u) {
            int s = __shfl(sB, (lane & 0x30) | u, 64);
            f[8 + u] = *(const h2*)(base + (unsigned)s * 64u + c4);
        }
#pragma unroll
        for (int u = 0; u < 8; ++u) {
            ax0 = dot2f(f[u], b10, ax0);
            ay0 = dot2f(f[u], b01, ay0);
            ax1 = dot2f(f[8 + u], b10, ax1);
            ay1 = dot2f(f[8 + u], b01, ay1);
        }
        sA = nA;
        sB = nB;
    }

    float dn = dinv[node];
    float ax = (ax0 + ax1) * dn, ay = (ay0 + ay1) * dn;
    int sl = pair * 2 + (c >> 3);  // aggT stays [8][N][16]
    aggT[((size_t)sl * n + node) * 8 + (c & 7)] = __floats2half2_rn(ax, ay);
}

// gatherT64: thP[2][N+1][32]; writes row-major fp32 out (+b2), 128B/group.
__global__ __launch_bounds__(NT) void gatherT64_k(
    const int* __restrict__ rowptr, const int* __restrict__ pdeg,
    const int* __restrict__ srcs, const float* __restrict__ dinv,
    const __half* __restrict__ thP, const float* __restrict__ b2,
    float* __restrict__ out, int n) {
    const int q8    = blockIdx.x & 7;
    const int pair  = q8 & 1;
    const int chunk = blockIdx.x >> 3;
    const int lane  = threadIdx.x & 63;
    const int wid   = threadIdx.x >> 6;
    const int g     = lane >> 4;
    const int c     = lane & 15;
    const int node  = chunk * 64 + (q8 >> 1) * 16 + wid * 4 + g;
    if (node >= n) return;

    const int e0 = rowptr[node];
    const int pd = pdeg[node];
    const char* base = (const char*)(thP + (size_t)pair * (n + 1) * 32);
    const unsigned c4 = (unsigned)c * 4u;
    const int c7 = c & 7;
    const h2 b10 = {(_Float16)1.0f, (_Float16)0.0f};
    const h2 b01 = {(_Float16)0.0f, (_Float16)1.0f};

    h2 fs = *(const h2*)(base + (size_t)node * 64 + c4);
    float ax0 = dot2f(fs, b10, 0.0f), ay0 = dot2f(fs, b01, 0.0f);
    float ax1 = 0.0f, ay1 = 0.0f;

    int sA = srcs[e0 + c7];
    int sB = srcs[e0 + 8 + c7];
    for (int jb = 0; jb < pd; jb += 16) {
        int nA = srcs[e0 + jb + 16 + c7];
        int nB = srcs[e0 + jb + 24 + c7];
        h2 f[16];
#pragma unroll
        for (int u = 0; u < 8; ++u) {
            int s = __shfl(sA, (lane & 0x30) | u, 64);
            f[u] = *(const h2*)(base + (unsigned)s * 64u + c4);
        }
#pragma unroll
        for (int u = 0; u < 8; ++u) {
            int s = __shfl(sB, (lane & 0x30) | u, 64);
            f[8 + u] = *(const h2*)(base + (unsigned)s * 64u + c4);
        }
#pragma unroll
        for (int u = 0; u < 8; ++u) {
            ax0 = dot2f(f[u], b10, ax0);
            ay0 = dot2f(f[u], b01, ay0);
            ax1 = dot2f(f[8 + u], b10, ax1);
            ay1 = dot2f(f[8 + u], b01, ay1);
        }
        sA = nA;
        sB = nB;
    }

    float dn = dinv[node];
    int col = pair * 32 + c * 2;
    *reinterpret_cast<float2*>(&out[(size_t)node * 64 + col]) =
        make_float2((ax0 + ax1) * dn + b2[col], (ay0 + ay1) * dn + b2[col + 1]);
}

// ---------------- fused MLP: thP = (relu(aggT@W1 + b1) @ W2) * dinv --------
__global__ __launch_bounds__(NT) void mgemm_fused_k(
    const __half* __restrict__ aggT, const float* __restrict__ W1,
    const float* __restrict__ b1, const float* __restrict__ W2,
    const float* __restrict__ dinv, __half* __restrict__ thP, int n) {
    __shared__ _Float16 h1s[64][136];

    const int wid  = threadIdx.x >> 6;
    const int lane = threadIdx.x & 63;
    const int lrow = lane & 15;
    const int kgrp = lane >> 4;

    if (blockIdx.x == 0 && threadIdx.x < 64) {
        int pr = threadIdx.x >> 5, j = threadIdx.x & 31;
        thP[((size_t)pr * (n + 1) + n) * 32 + j] = __float2half(0.0f);
    }

    half8 bf1[2][4];
    float bv[2];
#pragma unroll
    for (int nt = 0; nt < 2; ++nt) {
        int col = wid * 32 + nt * 16 + lrow;
#pragma unroll
        for (int kk = 0; kk < 4; ++kk)
#pragma unroll
            for (int j = 0; j < 8; ++j)
                bf1[nt][kk][j] = (_Float16)W1[(size_t)(kk * 32 + kgrp * 8 + j) * 128 + col];
        bv[nt] = b1[col];
    }
    half8 bf2[4];
    {
        int col = wid * 16 + lrow;
#pragma unroll
        for (int kk = 0; kk < 4; ++kk)
#pragma unroll
            for (int j = 0; j < 8; ++j)
                bf2[kk][j] = (_Float16)W2[(size_t)(kk * 32 + kgrp * 8 + j) * 64 + col];
    }

    const int m0 = blockIdx.x * 64;

    floatx4 acc1[4][2];
#pragma unroll
    for (int mt = 0; mt < 4; ++mt)
#pragma unroll
        for (int nt = 0; nt < 2; ++nt) acc1[mt][nt] = floatx4{0.f, 0.f, 0.f, 0.f};

#pragma unroll
    for (int kk = 0; kk < 4; ++kk) {
        const int k0 = kk * 32 + kgrp * 8;
        half8 af[4];
#pragma unroll
        for (int mt = 0; mt < 4; ++mt) {
            int row = m0 + mt * 16 + lrow;
            if (row >= n) row = n - 1;  // clamp; final stores guarded
            af[mt] = *reinterpret_cast<const half8*>(
                &aggT[(((size_t)(k0 >> 4)) * n + row) * 16 + (k0 & 15)]);
        }
#pragma unroll
        for (int mt = 0; mt < 4; ++mt)
#pragma unroll
            for (int nt = 0; nt < 2; ++nt)
                acc1[mt][nt] = __builtin_amdgcn_mfma_f32_16x16x32_f16(
                    af[mt], bf1[nt][kk], acc1[mt][nt], 0, 0, 0);
    }

#pragma unroll
    for (int mt = 0; mt < 4; ++mt) {
#pragma unroll
        for (int r = 0; r < 4; ++r) {
            int rloc = mt * 16 + kgrp * 4 + r;
#pragma unroll
            for (int nt = 0; nt < 2; ++nt) {
                float v = fmaxf(acc1[mt][nt][r] + bv[nt], 0.0f);
                h1s[rloc][wid * 32 + nt * 16 + lrow] = (_Float16)v;
            }
        }
    }
    __syncthreads();

    floatx4 acc2[4];
#pragma unroll
    for (int mt = 0; mt < 4; ++mt) acc2[mt] = floatx4{0.f, 0.f, 0.f, 0.f};

#pragma unroll
    for (int kk = 0; kk < 4; ++kk) {
        const int k0 = kk * 32 + kgrp * 8;
#pragma unroll
        for (int mt = 0; mt < 4; ++mt) {
            half8 af = *reinterpret_cast<const half8*>(&h1s[mt * 16 + lrow][k0]);
            acc2[mt] = __builtin_amdgcn_mfma_f32_16x16x32_f16(
                af, bf2[kk], acc2[mt], 0, 0, 0);
        }
    }

#pragma unroll
    for (int mt = 0; mt < 4; ++mt) {
#pragma unroll
        for (int r = 0; r < 4; ++r) {
            int row = m0 + mt * 16 + kgrp * 4 + r;
            if (row < n) {
                float v = acc2[mt][r] * dinv[row];
                int col = wid * 16 + lrow;
                thP[((size_t)(col >> 5) * (n + 1) + row) * 32 + (col & 31)] =
                    __float2half(v);
            }
        }
    }
}

// ---------------------------------------------------------------------------

extern "C" void kernel_launch(void* const* d_in, const int* in_sizes, int n_in,
                              void* d_out, int out_size, void* d_ws, size_t ws_size,
                              hipStream_t stream) {
    const float* x   = (const float*)d_in[0];
    const int*   ei  = (const int*)d_in[1];
    const float* W1  = (const float*)d_in[2];
    const float* b1  = (const float*)d_in[3];
    const float* W2  = (const float*)d_in[4];
    const float* b2  = (const float*)d_in[5];
    float*       out = (float*)d_out;

    const int N = in_sizes[0] / 128;
    const int E = in_sizes[1] / 2;
    const int* srcp = ei;      // edge_index[0]
    const int* dstp = ei + E;  // edge_index[1]

    // workspace (512B-aligned):
    //   dinv[N] | pdeg[N] | rowptr[N] | bktcur[128] | srcs[128*SCAP]
    //   | xhP[4][N+1][32] fp16 | aggT[8][N][16] fp16
    //   | thP[2][N+1][32] fp16  (pairs[128*CAP] u32 aliases thP: 10.5<12.8MB)
    char* ws = (char*)d_ws;
    size_t off = 0;
    auto alloc = [&](size_t bytes) {
        char* p = ws + off;
        off = (off + bytes + 511) & ~(size_t)511;
        return p;
    };
    float*  dinv   = (float*)alloc((size_t)N * 4);
    int*    pdeg   = (int*)alloc((size_t)N * 4);
    int*    rowptr = (int*)alloc((size_t)N * 4);
    int*    bktcur = (int*)alloc(128 * 4);
    int*    srcs   = (int*)alloc((size_t)128 * SCAP * 4);
    __half* xhP    = (__half*)alloc((size_t)(N + 1) * 128 * 2);
    __half* aggT   = (__half*)alloc((size_t)N * 128 * 2);
    __half* thP    = (__half*)alloc((size_t)(N + 1) * 64 * 2);
    unsigned* pairs = (unsigned*)thP;  // alias: dead until mgemm_fused

    // ---- CSR build: bin -> per-bucket build+scatter ----
    hipMemsetAsync(bktcur, 0, 128 * 4, stream);
    binA_k<<<(E + NT * KE - 1) / (NT * KE), NT, 0, stream>>>(
        srcp, dstp, bktcur, pairs, E);
    scatB_k<<<128, 1024, 0, stream>>>(pairs, bktcur, rowptr, pdeg, dinv, srcs, N);

    // ---- layer 1: xhP (dummy row zeroed) -> aggT ----
    conv1T_k<<<((N + 1) * 8 + NT - 1) / NT, NT, 0, stream>>>(x, dinv, xhP, N);
    gatherT128_k<<<((N + 31) / 32) * 8, NT, 0, stream>>>(
        rowptr, pdeg, srcs, dinv, xhP, (__half2*)aggT, N);

    // ---- fused MLP: aggT -> thP = (relu(aggT@W1+b1)@W2)*dinv ----
    mgemm_fused_k<<<(N + 63) / 64, NT, 0, stream>>>(
        aggT, W1, b1, W2, dinv, thP, N);

    // ---- layer 2 gather -> out (+b2) ----
    gatherT64_k<<<((N + 63) / 64) * 8, NT, 0, stream>>>(
        rowptr, pdeg, srcs, dinv, thP, b2, out, N);
}